// Round 1
// 422.454 us; speedup vs baseline: 1.2237x; 1.2237x over previous
//
#include <hip/hip_runtime.h>

#define B_   4
#define CO   256
#define CIN  1024
#define CQ   32
#define HN   16384
#define NPIX 65536                       // B_*HN flat pixels
#define NTOT ((size_t)B_ * CO * HN)

typedef unsigned short ushort_t;
typedef __attribute__((ext_vector_type(8))) short bf16x8;
typedef __attribute__((ext_vector_type(4))) float f32x4;

__device__ __forceinline__ unsigned bf16pair(float x, float y) {
    unsigned xu = __float_as_uint(x), yu = __float_as_uint(y);
    unsigned xr = (xu + 0x7FFFu + ((xu >> 16) & 1u)) >> 16;
    unsigned yr = (yu + 0x7FFFu + ((yu >> 16) & 1u)) >> 16;
    return xr | (yr << 16);
}
__device__ __forceinline__ ushort_t bf16of(float x) {
    unsigned u = __float_as_uint(x);
    return (ushort_t)((u + 0x7FFFu + ((u >> 16) & 1u)) >> 16);
}
__device__ __forceinline__ float bf2f(ushort_t h) {
    return __uint_as_float(((unsigned)h) << 16);
}
__device__ __forceinline__ void unpack8(uint4 u, float* f) {
    f[0] = __uint_as_float(u.x << 16); f[1] = __uint_as_float(u.x & 0xffff0000u);
    f[2] = __uint_as_float(u.y << 16); f[3] = __uint_as_float(u.y & 0xffff0000u);
    f[4] = __uint_as_float(u.z << 16); f[5] = __uint_as_float(u.z & 0xffff0000u);
    f[6] = __uint_as_float(u.w << 16); f[7] = __uint_as_float(u.w & 0xffff0000u);
}
// async global->LDS, 16B per lane. lds must be wave-uniform; lane i lands at lds + i*16.
__device__ __forceinline__ void async16(void* lds, const void* g) {
    __builtin_amdgcn_global_load_lds(
        (const __attribute__((address_space(1))) void*)g,
        (__attribute__((address_space(3))) void*)lds, 16, 0, 0);
}

// ---------------------------------------------------------------------------
// weights fp32 -> bf16 (w_conv, wq|wk fused rows 0-31/32-63, wv)
// ---------------------------------------------------------------------------
__global__ __launch_bounds__(256) void wcvt(
    const float* __restrict__ w, const float* __restrict__ wq,
    const float* __restrict__ wk, const float* __restrict__ wv,
    ushort_t* __restrict__ w_bf, ushort_t* __restrict__ wqk_bf,
    ushort_t* __restrict__ wv_bf)
{
    int i = blockIdx.x * 256 + threadIdx.x;          // 0..344063
    if (i < 262144) {
        w_bf[i] = bf16of(w[i]);
    } else if (i < 278528) {
        int l = i - 262144; int row = l >> 8, col = l & 255;
        float v = (row < 32) ? wq[row * 256 + col] : wk[(row - 32) * 256 + col];
        wqk_bf[l] = bf16of(v);
    } else {
        int l = i - 278528;
        wv_bf[l] = bf16of(wv[l]);
    }
}

// ---------------------------------------------------------------------------
// conv: x[b,o,n] = sum_c w[o,c]*fcat[b,c,n], bf16 MFMA, out bf16.
// o-tile 128 x n-tile 128, BK 32. Double-buffered LDS, 1 barrier/K-step,
// cross-iteration register prefetch of the fp32 B operand.
// A (weights) via granule-swizzled global_load_lds into Aw[o][32].
// B (fcat) via k-grouped coalesced dword loads -> bf16 -> LDS [n][40]
// (80B stride, 8B-granule XOR swizzle) so both frags are ds_read_b128.
// ---------------------------------------------------------------------------
__global__ __launch_bounds__(256) void conv_mfma3(
    const float* __restrict__ s5, const float* __restrict__ s4,
    const float* __restrict__ s3, const float* __restrict__ s2,
    const ushort_t* __restrict__ w_bf, ushort_t* __restrict__ xb)
{
    __shared__ ushort_t Aw[2][128 * 32];   // [o][k], granule-swizzled cols
    __shared__ ushort_t Bn[2][128 * 40];   // [n][k], stride 40, swizzled cols
    const int o0 = blockIdx.x * 128;
    const int n0 = blockIdx.y * 128;
    const int b  = blockIdx.z;
    const int tid = threadIdx.x;
    const int wave = tid >> 6, lane = tid & 63, l15 = lane & 15, quad = lane >> 4;
    const int wm = wave & 1, wn = wave >> 1;
    const int n_st = tid & 127;            // staging pixel within tile
    const int kqb  = tid >> 7;             // staging k-granule base (0/1)
    const int bswz = ((n_st >> 3) & 3) << 1;
    f32x4 acc[4][4] = {};
    float v[4][4];

    auto loadB = [&](int k0) {
        const float* base = (k0 < 256) ? s5 : (k0 < 512) ? s4
                          : (k0 < 768) ? s3 : s2;
        const float* sp = base + ((size_t)b * 256 + (k0 & 255)) * HN + n0 + n_st;
        #pragma unroll
        for (int i = 0; i < 4; ++i) {
            const float* cp = sp + (size_t)(kqb + 2 * i) * 4 * HN;
            #pragma unroll
            for (int j = 0; j < 4; ++j) v[i][j] = cp[(size_t)j * HN];
        }
    };
    auto storeB = [&](int bi) {
        ushort_t* Bp = Bn[bi];
        #pragma unroll
        for (int i = 0; i < 4; ++i) {
            int pos = (kqb + 2 * i) ^ bswz;
            uint2 u = make_uint2(bf16pair(v[i][0], v[i][1]),
                                 bf16pair(v[i][2], v[i][3]));
            *(uint2*)&Bp[n_st * 40 + pos * 4] = u;
        }
    };
    auto issueA = [&](int k0, int bi) {
        #pragma unroll
        for (int r = 0; r < 2; ++r) {
            int row  = r * 64 + wave * 16;
            int orow = row + (lane >> 2);
            const ushort_t* g = w_bf + (size_t)(o0 + orow) * CIN + k0
                                + (((lane & 3) ^ ((orow >> 1) & 3)) << 3);
            async16(&Aw[bi][row * 32], g);
        }
    };

    // prologue: stage k0=0 into buffer 0
    issueA(0, 0);
    loadB(0);
    storeB(0);

    int buf = 0;
    for (int k0 = 0; k0 < CIN; k0 += 32) {
        __syncthreads();                     // Aw[buf]/Bn[buf] ready
        const bool more = (k0 + 32 < CIN);
        if (more) { issueA(k0 + 32, buf ^ 1); loadB(k0 + 32); }
        bf16x8 af[4], bfv[4];
        #pragma unroll
        for (int tm = 0; tm < 4; ++tm) {
            int orow = wm * 64 + tm * 16 + l15;
            int pos  = quad ^ ((orow >> 1) & 3);
            af[tm] = *(const bf16x8*)&Aw[buf][orow * 32 + pos * 8];
        }
        #pragma unroll
        for (int tn = 0; tn < 4; ++tn) {
            int nl = wn * 64 + tn * 16 + l15;
            int p0 = (2 * quad) ^ (((nl >> 3) & 3) << 1);
            bfv[tn] = *(const bf16x8*)&Bn[buf][nl * 40 + p0 * 4];
        }
        #pragma unroll
        for (int tm = 0; tm < 4; ++tm)
            #pragma unroll
            for (int tn = 0; tn < 4; ++tn)
                acc[tm][tn] = __builtin_amdgcn_mfma_f32_16x16x32_bf16(
                    af[tm], bfv[tn], acc[tm][tn], 0, 0, 0);
        if (more) storeB(buf ^ 1);           // convert waits on vmcnt here
        buf ^= 1;
    }
    #pragma unroll
    for (int tm = 0; tm < 4; ++tm)
        #pragma unroll
        for (int r = 0; r < 4; ++r) {
            int o = o0 + wm * 64 + tm * 16 + quad * 4 + r;
            size_t base = ((size_t)b * CO + o) * HN + n0;
            #pragma unroll
            for (int tn = 0; tn < 4; ++tn)
                xb[base + wn * 64 + tn * 16 + l15] = bf16of(acc[tm][tn][r]);
        }
}

// ---------------------------------------------------------------------------
// BN stats: atomic per-channel sum/sumsq from bf16 x
// ---------------------------------------------------------------------------
__global__ __launch_bounds__(256) void bn_stats(
    const ushort_t* __restrict__ xb, float* __restrict__ accum)
{
    const int o = blockIdx.x, seg = blockIdx.y, tid = threadIdx.x;
    const int wave = tid >> 6, lane = tid & 63;
    float s = 0.f, ss = 0.f;
    for (int b = 0; b < B_; ++b) {
        const ushort_t* p = xb + ((size_t)(b * CO + o)) * HN + seg * 2048 + tid * 8;
        uint4 u = *(const uint4*)p;
        float f[8]; unpack8(u, f);
        #pragma unroll
        for (int j = 0; j < 8; ++j) { s += f[j]; ss += f[j] * f[j]; }
    }
    #pragma unroll
    for (int m = 1; m < 64; m <<= 1) { s += __shfl_xor(s, m); ss += __shfl_xor(ss, m); }
    __shared__ float shs[4], shss[4];
    if (lane == 0) { shs[wave] = s; shss[wave] = ss; }
    __syncthreads();
    if (tid == 0) {
        atomicAdd(&accum[o],       shs[0] + shs[1] + shs[2] + shs[3]);
        atomicAdd(&accum[256 + o], shss[0] + shss[1] + shss[2] + shss[3]);
    }
}

__global__ __launch_bounds__(256) void bn_finalize(
    const float* __restrict__ accum, const float* __restrict__ g,
    const float* __restrict__ bt, float* __restrict__ scale,
    float* __restrict__ shift)
{
    int o = threadIdx.x;
    float mu  = accum[o] / (float)NPIX;
    float var = accum[256 + o] / (float)NPIX - mu * mu;
    float sc  = g[o] * rsqrtf(var + 1e-5f);
    scale[o] = sc;
    shift[o] = bt[o] - mu * sc;
}

// ---------------------------------------------------------------------------
// BN+ReLU + transpose: xb [b][c][n] bf16 -> featT [flat n][c] bf16 (64x64 tiles)
// ---------------------------------------------------------------------------
__global__ __launch_bounds__(256) void bnrelu_t(
    const ushort_t* __restrict__ xb, const float* __restrict__ scale,
    const float* __restrict__ shift, ushort_t* __restrict__ featT)
{
    __shared__ ushort_t sh[64 * 68];
    const int hn0 = blockIdx.x * 64, c0 = blockIdx.y * 64, b = blockIdx.z;
    const int tid = threadIdx.x;
    {
        int cl = tid >> 2, seg = tid & 3;
        float sc = scale[c0 + cl], sf = shift[c0 + cl];
        const ushort_t* src = xb + ((size_t)(b * CO + c0 + cl)) * HN + hn0 + seg * 16;
        #pragma unroll
        for (int h = 0; h < 2; ++h) {
            uint4 u = *(const uint4*)(src + h * 8);
            float f[8]; unpack8(u, f);
            #pragma unroll
            for (int j = 0; j < 8; ++j) {
                float v = fmaxf(fmaf(sc, f[j], sf), 0.f);
                sh[(seg * 16 + h * 8 + j) * 68 + cl] = bf16of(v);
            }
        }
    }
    __syncthreads();
    {
        int nl = tid >> 2, seg = tid & 3;
        size_t gn = (size_t)b * HN + hn0 + nl;
        ushort_t* dst = featT + gn * CO + c0 + seg * 16;
        #pragma unroll
        for (int j = 0; j < 4; ++j)
            *(uint2*)(dst + j * 4) = *(const uint2*)&sh[nl * 68 + seg * 16 + j * 4];
    }
}

// ---------------------------------------------------------------------------
// QK projection: D[n][64ch] = featT x wqk^T, + bias, per-pixel L2 norm.
// Writes Qt [n][32] bf16, K TRANSPOSED -> KtT [b][q][n] bf16 (for fused KV),
// Ksum atomics. Clean DMA GEMM, K=256.
// ---------------------------------------------------------------------------
__global__ __launch_bounds__(256) void qk_mfma(
    const ushort_t* __restrict__ featT, const ushort_t* __restrict__ wqk_bf,
    const float* __restrict__ bq, const float* __restrict__ bk,
    ushort_t* __restrict__ Qt, ushort_t* __restrict__ KtT,
    float* __restrict__ Ksum)
{
    __shared__ ushort_t At[128 * 32];
    __shared__ ushort_t Bt[64 * 32];
    const int n0 = blockIdx.x * 128;       // flat pixel
    const int b  = n0 >> 14;
    const int hn0 = n0 & 16383;
    const int tid = threadIdx.x;
    const int wave = tid >> 6, lane = tid & 63, l15 = lane & 15, quad = lane >> 4;
    const int nsub = (wave & 1) * 64;
    const int isK  = wave >> 1;
    f32x4 acc[4][2] = {};

    for (int k0 = 0; k0 < CO; k0 += 32) {
        #pragma unroll
        for (int r = 0; r < 2; ++r) {
            int row = r * 64 + wave * 16;
            const ushort_t* g = featT + (size_t)(n0 + row + (lane >> 2)) * CO
                                + k0 + (lane & 3) * 8;
            async16(&At[row * 32], g);
        }
        {
            int row = wave * 16;
            const ushort_t* g = wqk_bf + (size_t)(row + (lane >> 2)) * CO
                                + k0 + (lane & 3) * 8;
            async16(&Bt[row * 32], g);
        }
        __syncthreads();
        bf16x8 af[4], bfv[2];
        #pragma unroll
        for (int tm = 0; tm < 4; ++tm)
            af[tm] = *(const bf16x8*)&At[(nsub + tm * 16 + l15) * 32 + quad * 8];
        #pragma unroll
        for (int tc = 0; tc < 2; ++tc)
            bfv[tc] = *(const bf16x8*)&Bt[(isK * 32 + tc * 16 + l15) * 32 + quad * 8];
        #pragma unroll
        for (int tm = 0; tm < 4; ++tm)
            #pragma unroll
            for (int tc = 0; tc < 2; ++tc)
                acc[tm][tc] = __builtin_amdgcn_mfma_f32_16x16x32_bf16(
                    af[tm], bfv[tc], acc[tm][tc], 0, 0, 0);
        __syncthreads();
    }
    const float bias0 = isK ? bk[l15]      : bq[l15];
    const float bias1 = isK ? bk[16 + l15] : bq[16 + l15];
    float ks0 = 0.f, ks1 = 0.f;
    #pragma unroll
    for (int tm = 0; tm < 4; ++tm)
        #pragma unroll
        for (int r = 0; r < 4; ++r) {
            float v0 = acc[tm][0][r] + bias0;
            float v1 = acc[tm][1][r] + bias1;
            float sq = v0 * v0 + v1 * v1;
            sq += __shfl_xor(sq, 1); sq += __shfl_xor(sq, 2);
            sq += __shfl_xor(sq, 4); sq += __shfl_xor(sq, 8);
            float inv = 1.f / fmaxf(sqrtf(sq), 1e-6f);
            v0 *= inv; v1 *= inv;
            if (isK) {
                int hn = hn0 + nsub + tm * 16 + quad * 4 + r;
                KtT[((size_t)(b * CQ + l15)) * HN + hn]      = bf16of(v0);
                KtT[((size_t)(b * CQ + 16 + l15)) * HN + hn] = bf16of(v1);
            } else {
                int n = n0 + nsub + tm * 16 + quad * 4 + r;
                Qt[(size_t)n * CQ + l15]      = bf16of(v0);
                Qt[(size_t)n * CQ + 16 + l15] = bf16of(v1);
            }
            ks0 += v0; ks1 += v1;
        }
    if (isK) {
        ks0 += __shfl_xor(ks0, 16); ks0 += __shfl_xor(ks0, 32);
        ks1 += __shfl_xor(ks1, 16); ks1 += __shfl_xor(ks1, 32);
        if (quad == 0) {
            atomicAdd(&Ksum[b * CQ + l15],      ks0);
            atomicAdd(&Ksum[b * CQ + 16 + l15], ks1);
        }
    }
}

// ---------------------------------------------------------------------------
// V projection fused with KV: V never hits global. V-tile (+bias) is kept in
// LDS [c][n] and multiplied against KtT via a per-wave MFMA GEMM; fp32 atomic
// accumulate into matT[b][c][q]. Vsum atomics as before.
// ---------------------------------------------------------------------------
__global__ __launch_bounds__(256) void v_kv_mfma(
    const ushort_t* __restrict__ featT, const ushort_t* __restrict__ wv_bf,
    const float* __restrict__ bv, const ushort_t* __restrict__ KtT,
    float* __restrict__ matT, float* __restrict__ Vsum)
{
    __shared__ ushort_t sh[128 * 136];            // 34.8 KB
    ushort_t* At = sh;                             // [128][32] during k-loop
    ushort_t* Bt = sh + 4096;                      // [128][32]
    const int n0  = blockIdx.x * 128;              // flat pixel
    const int co0 = blockIdx.y * 128;
    const int b   = n0 >> 14;
    const int hn0 = n0 & 16383;
    const int tid = threadIdx.x;
    const int wave = tid >> 6, lane = tid & 63, l15 = lane & 15, quad = lane >> 4;
    const int wm = wave & 1, wn = wave >> 1;
    f32x4 acc[4][4] = {};

    for (int k0 = 0; k0 < CO; k0 += 32) {
        #pragma unroll
        for (int r = 0; r < 2; ++r) {
            int row = r * 64 + wave * 16;
            const ushort_t* ga = featT + (size_t)(n0 + row + (lane >> 2)) * CO
                                 + k0 + (lane & 3) * 8;
            async16(&At[row * 32], ga);
            const ushort_t* gb = wv_bf + (size_t)(co0 + row + (lane >> 2)) * CO
                                 + k0 + (lane & 3) * 8;
            async16(&Bt[row * 32], gb);
        }
        __syncthreads();
        bf16x8 af[4], bfv[4];
        #pragma unroll
        for (int tm = 0; tm < 4; ++tm)
            af[tm] = *(const bf16x8*)&At[(wm * 64 + tm * 16 + l15) * 32 + quad * 8];
        #pragma unroll
        for (int tn = 0; tn < 4; ++tn)
            bfv[tn] = *(const bf16x8*)&Bt[(wn * 64 + tn * 16 + l15) * 32 + quad * 8];
        #pragma unroll
        for (int tm = 0; tm < 4; ++tm)
            #pragma unroll
            for (int tn = 0; tn < 4; ++tn)
                acc[tm][tn] = __builtin_amdgcn_mfma_f32_16x16x32_bf16(
                    af[tm], bfv[tn], acc[tm][tn], 0, 0, 0);
        __syncthreads();
    }
    // epilogue A: bias, Vsum, pack V -> Vlds [c][136]  (aliases At/Bt: safe,
    // last k-iteration ended with __syncthreads)
    ushort_t* Vlds = sh;
    float bvl[4], vsum_p[4] = {};
    #pragma unroll
    for (int tn = 0; tn < 4; ++tn) bvl[tn] = bv[co0 + wn * 64 + tn * 16 + l15];
    #pragma unroll
    for (int tm = 0; tm < 4; ++tm)
        #pragma unroll
        for (int tn = 0; tn < 4; ++tn) {
            float x0 = acc[tm][tn][0] + bvl[tn];
            float x1 = acc[tm][tn][1] + bvl[tn];
            float x2 = acc[tm][tn][2] + bvl[tn];
            float x3 = acc[tm][tn][3] + bvl[tn];
            vsum_p[tn] += (x0 + x1) + (x2 + x3);
            uint2 u = make_uint2(bf16pair(x0, x1), bf16pair(x2, x3));
            int c_loc = wn * 64 + tn * 16 + l15;
            int nb    = wm * 64 + tm * 16 + quad * 4;   // r=0..3 contiguous n
            *(uint2*)&Vlds[c_loc * 136 + nb] = u;
        }
    #pragma unroll
    for (int tn = 0; tn < 4; ++tn) {
        float s = vsum_p[tn];
        s += __shfl_xor(s, 16); s += __shfl_xor(s, 32);
        if (quad == 0)
            atomicAdd(&Vsum[b * CO + co0 + wn * 64 + tn * 16 + l15], s);
    }
    __syncthreads();
    // epilogue B: matT[c][q] += sum_n V[n][c]*K[n][q]; wave owns 32 c-rows.
    f32x4 acc2[2][2] = {};
    #pragma unroll
    for (int ks = 0; ks < 4; ++ks) {
        bf16x8 a2[2], b2[2];
        #pragma unroll
        for (int t2 = 0; t2 < 2; ++t2)
            a2[t2] = *(const bf16x8*)&Vlds[(wave * 32 + t2 * 16 + l15) * 136
                                           + ks * 32 + quad * 8];
        #pragma unroll
        for (int tc = 0; tc < 2; ++tc)
            b2[tc] = *(const bf16x8*)&KtT[((size_t)(b * CQ + tc * 16 + l15)) * HN
                                          + hn0 + ks * 32 + quad * 8];
        #pragma unroll
        for (int t2 = 0; t2 < 2; ++t2)
            #pragma unroll
            for (int tc = 0; tc < 2; ++tc)
                acc2[t2][tc] = __builtin_amdgcn_mfma_f32_16x16x32_bf16(
                    a2[t2], b2[tc], acc2[t2][tc], 0, 0, 0);
    }
    #pragma unroll
    for (int t2 = 0; t2 < 2; ++t2)
        #pragma unroll
        for (int tc = 0; tc < 2; ++tc)
            #pragma unroll
            for (int r = 0; r < 4; ++r) {
                int c = co0 + wave * 32 + t2 * 16 + quad * 4 + r;
                atomicAdd(&matT[b * 8192 + c * CQ + tc * 16 + l15],
                          acc2[t2][tc][r]);
            }
}

// ---------------------------------------------------------------------------
// tailor[n] = 1 / max(HN + Qn[n].Ksum[b], 1e-6)
// ---------------------------------------------------------------------------
__global__ __launch_bounds__(256) void tailor_k(
    const ushort_t* __restrict__ Qt, const float* __restrict__ Ksum,
    float* __restrict__ tailor)
{
    __shared__ float ks[CQ];
    const int n = blockIdx.x * 256 + threadIdx.x;
    const int b = n >> 14;
    if (threadIdx.x < CQ) ks[threadIdx.x] = Ksum[b * CQ + threadIdx.x];
    __syncthreads();
    const uint4* q = (const uint4*)&Qt[(size_t)n * CQ];
    float e = 0.f;
    #pragma unroll
    for (int i = 0; i < 4; ++i) {
        float f[8]; unpack8(q[i], f);
        #pragma unroll
        for (int j = 0; j < 8; ++j) e += f[j] * ks[i * 8 + j];
    }
    tailor[n] = 1.f / fmaxf((float)HN + e, 1e-6f);
}

// ---------------------------------------------------------------------------
// final: out[b,c,hn] = nan2num(gamma*(Vsum[c] + sum_q matT[c][q]Qt[n][q])*tailor[n])
//        + relu(scale[c]*x[b,c,hn]+shift[c]).  Single-K-step MFMA, no LDS.
// ---------------------------------------------------------------------------
__global__ __launch_bounds__(256) void final_mfma(
    const ushort_t* __restrict__ xb, const ushort_t* __restrict__ Qt,
    const float* __restrict__ matT, const float* __restrict__ Vsum,
    const float* __restrict__ tailor, const float* __restrict__ scale,
    const float* __restrict__ shift, const float* __restrict__ gamma_p,
    float* __restrict__ out)
{
    const int c0 = blockIdx.x * 128;
    const int n0 = blockIdx.y * 128;       // flat pixel
    const int b  = n0 >> 14, hn0 = n0 & 16383;
    const int tid = threadIdx.x;
    const int wave = tid >> 6, lane = tid & 63, l15 = lane & 15, quad = lane >> 4;
    const int wm = wave & 1, wn = wave >> 1;
    const float gamma = gamma_p[0];

    bf16x8 af[4], bfv[4];
    #pragma unroll
    for (int tm = 0; tm < 4; ++tm) {
        int c = c0 + wm * 64 + tm * 16 + l15;
        const float* mp = matT + b * 8192 + c * CQ + quad * 8;
        float4 m0 = *(const float4*)mp;
        float4 m1 = *(const float4*)(mp + 4);
        union { bf16x8 v; unsigned u[4]; } t;
        t.u[0] = bf16pair(m0.x, m0.y); t.u[1] = bf16pair(m0.z, m0.w);
        t.u[2] = bf16pair(m1.x, m1.y); t.u[3] = bf16pair(m1.z, m1.w);
        af[tm] = t.v;
    }
    #pragma unroll
    for (int tn = 0; tn < 4; ++tn) {
        int n = n0 + wn * 64 + tn * 16 + l15;
        bfv[tn] = *(const bf16x8*)&Qt[(size_t)n * CQ + quad * 8];
    }
    f32x4 acc[4][4] = {};
    #pragma unroll
    for (int tm = 0; tm < 4; ++tm)
        #pragma unroll
        for (int tn = 0; tn < 4; ++tn)
            acc[tm][tn] = __builtin_amdgcn_mfma_f32_16x16x32_bf16(
                af[tm], bfv[tn], acc[tm][tn], 0, 0, 0);

    float tl[4];
    #pragma unroll
    for (int tn = 0; tn < 4; ++tn) tl[tn] = tailor[n0 + wn * 64 + tn * 16 + l15];

    #pragma unroll
    for (int tm = 0; tm < 4; ++tm)
        #pragma unroll
        for (int r = 0; r < 4; ++r) {
            int c = c0 + wm * 64 + tm * 16 + quad * 4 + r;
            float vs = Vsum[b * CO + c];
            float sc = scale[c], sf = shift[c];
            size_t rowbase = ((size_t)(b * CO + c)) * HN + hn0;
            #pragma unroll
            for (int tn = 0; tn < 4; ++tn) {
                int nl = wn * 64 + tn * 16 + l15;
                float val = gamma * (acc[tm][tn][r] + vs) * tl[tn];
                if (isnan(val)) val = 0.f;
                else if (isinf(val)) val = (val > 0.f) ? 1.f : -1.f;
                float feat = fmaxf(fmaf(sc, bf2f(xb[rowbase + nl]), sf), 0.f);
                out[rowbase + nl] = val + feat;
            }
        }
}

// ---------------------------------------------------------------------------
extern "C" void kernel_launch(void* const* d_in, const int* in_sizes, int n_in,
                              void* d_out, int out_size, void* d_ws, size_t ws_size,
                              hipStream_t stream)
{
    const float* s5      = (const float*)d_in[0];
    const float* s4      = (const float*)d_in[1];
    const float* s3      = (const float*)d_in[2];
    const float* s2      = (const float*)d_in[3];
    const float* w_conv  = (const float*)d_in[4];
    const float* bn_g    = (const float*)d_in[5];
    const float* bn_b    = (const float*)d_in[6];
    const float* wq      = (const float*)d_in[7];
    const float* bq      = (const float*)d_in[8];
    const float* wk      = (const float*)d_in[9];
    const float* bk      = (const float*)d_in[10];
    const float* wv      = (const float*)d_in[11];
    const float* bv      = (const float*)d_in[12];
    const float* gamma_p = (const float*)d_in[13];

    char* p = (char*)d_ws;
    ushort_t* xb     = (ushort_t*)p;  p += NTOT * 2;                 // 32 MB
    ushort_t* featT  = (ushort_t*)p;  p += NTOT * 2;                 // 32 MB
    ushort_t* Qt     = (ushort_t*)p;  p += (size_t)NPIX * CQ * 2;    // 4 MB
    ushort_t* KtT    = (ushort_t*)p;  p += (size_t)NPIX * CQ * 2;    // 4 MB
    ushort_t* w_bf   = (ushort_t*)p;  p += (size_t)CO * CIN * 2;     // 512 KB
    ushort_t* wqk_bf = (ushort_t*)p;  p += 64 * CO * 2;              // 32 KB
    ushort_t* wv_bf  = (ushort_t*)p;  p += (size_t)CO * CO * 2;      // 128 KB
    float* matT  = (float*)p;                                        // 32768 f
    float* Ksum  = matT + (size_t)B_ * CO * CQ;                      // 128 f
    float* Vsum  = Ksum + B_ * CQ;                                   // 1024 f
    float* accum = Vsum + B_ * CO;                                   // 512 f
    size_t zero_bytes = (size_t)(32768 + 128 + 1024 + 512) * 4;
    p += zero_bytes;
    float* scale  = (float*)p;  p += 256 * 4;
    float* shift  = (float*)p;  p += 256 * 4;
    float* tailor = (float*)p;  p += (size_t)NPIX * 4;

    hipMemsetAsync(matT, 0, zero_bytes, stream);
    wcvt<<<1344, 256, 0, stream>>>(w_conv, wq, wk, wv, w_bf, wqk_bf, wv_bf);
    conv_mfma3<<<dim3(2, 128, B_), 256, 0, stream>>>(s5, s4, s3, s2, w_bf, xb);
    bn_stats<<<dim3(256, 8), 256, 0, stream>>>(xb, accum);
    bn_finalize<<<1, 256, 0, stream>>>(accum, bn_g, bn_b, scale, shift);
    bnrelu_t<<<dim3(256, 4, B_), 256, 0, stream>>>(xb, scale, shift, featT);
    qk_mfma<<<512, 256, 0, stream>>>(featT, wqk_bf, bq, bk, Qt, KtT, Ksum);
    tailor_k<<<256, 256, 0, stream>>>(Qt, Ksum, tailor);
    v_kv_mfma<<<dim3(512, 2), 256, 0, stream>>>(featT, wv_bf, bv, KtT, matT, Vsum);
    final_mfma<<<dim3(2, 512), 256, 0, stream>>>(xb, Qt, matT, Vsum, tailor,
                                                 scale, shift, gamma_p,
                                                 (float*)d_out);
}